// Round 15
// baseline (88330.200 us; speedup 1.0000x reference)
//
#include <hip/hip_runtime.h>
#include <cstdint>
#include <math.h>

typedef unsigned int u32;

#define BB 256   // batch
#define NN 256   // nodes
#define EE 256   // enc dim
#define HH 512   // hidden
#define G4 2048  // 4H
#define KK 768   // E + H
#define TT 256   // steps
#define NBLK 256
#define NTHR 1024

#define ALOADD(p)    __hip_atomic_load((p), __ATOMIC_RELAXED, __HIP_MEMORY_SCOPE_AGENT)
#define ASTORED(p,v) __hip_atomic_store((p), (v), __ATOMIC_RELAXED, __HIP_MEMORY_SCOPE_AGENT)
#define ALOADI(p)    __hip_atomic_load((p), __ATOMIC_RELAXED, __HIP_MEMORY_SCOPE_AGENT)
#define ASTOREI(p,v) __hip_atomic_store((p), (v), __ATOMIC_RELAXED, __HIP_MEMORY_SCOPE_AGENT)

// ---------------- Threefry-2x32, exactly as jax/_src/prng.py ----------------
__device__ __forceinline__ u32 rotl(u32 x, int d) { return (x << d) | (x >> (32 - d)); }

__device__ __forceinline__ void tf4(u32& x0, u32& x1, int r0, int r1, int r2, int r3) {
  x0 += x1; x1 = rotl(x1, r0); x1 ^= x0;
  x0 += x1; x1 = rotl(x1, r1); x1 ^= x0;
  x0 += x1; x1 = rotl(x1, r2); x1 ^= x0;
  x0 += x1; x1 = rotl(x1, r3); x1 ^= x0;
}

__device__ __forceinline__ void threefry2x32(u32 k0, u32 k1, u32 x0, u32 x1, u32& o0, u32& o1) {
  u32 k2 = k0 ^ k1 ^ 0x1BD11BDAu;
  x0 += k0; x1 += k1;
  tf4(x0, x1, 13, 15, 26, 6);  x0 += k1; x1 += k2 + 1u;
  tf4(x0, x1, 17, 29, 16, 24); x0 += k2; x1 += k0 + 2u;
  tf4(x0, x1, 13, 15, 26, 6);  x0 += k0; x1 += k1 + 3u;
  tf4(x0, x1, 17, 29, 16, 24); x0 += k1; x1 += k2 + 4u;
  tf4(x0, x1, 13, 15, 26, 6);  x0 += k2; x1 += k0 + 5u;
  o0 = x0; o1 = x1;
}

struct Args {
  const float *enc, *W_ih, *W_hh, *b_ih, *b_hh, *W_q, *W_k, *v;
  float *out;
  float *kT;       // [B][H][N] f32
  float *Wc;       // [K=768][2048] f32, gate-interleaved permuted columns
  float *WqT;      // [H][H] f32 k-major
  double *bsum;    // [2048]
  u32 *keys;       // [256][2]
  double *h0, *h1; // [B][H] double-buffered hidden (LLC-coherent)
  double *c;       // [B][H] (private per A-block)
  double *q;       // [B][H] fp64 q (LLC-coherent)
  int *idx;        // [B] last sampled index (LLC-coherent)
  u32 *flags;      // [0]=p1f | [256]=qf | [512]=p2f | [768]=cnt | [800]=gen
};

// Full grid barrier with cache maintenance — used ONCE after phase 0.
__device__ __forceinline__ void grid_barrier(u32* cnt, u32* gen) {
  __syncthreads();
  if (threadIdx.x == 0) {
    u32 g = __hip_atomic_load(gen, __ATOMIC_RELAXED, __HIP_MEMORY_SCOPE_AGENT);
    __threadfence();
    if (atomicAdd(cnt, 1u) == NBLK - 1u) {
      __hip_atomic_store(cnt, 0u, __ATOMIC_RELAXED, __HIP_MEMORY_SCOPE_AGENT);
      __threadfence();
      atomicAdd(gen, 1u);
    } else {
      while (__hip_atomic_load(gen, __ATOMIC_RELAXED, __HIP_MEMORY_SCOPE_AGENT) == g) {
        __builtin_amdgcn_s_sleep(2);
      }
    }
    __threadfence();
  }
  __syncthreads();
}

// Flag-array pod handoff (r9-proven).
__device__ __forceinline__ void pod_signal(u32* ph, int pod, int me, u32 val) {
  asm volatile("s_waitcnt vmcnt(0)" ::: "memory");
  __syncthreads();
  if (threadIdx.x == 0) ASTOREI(&ph[pod * 32 + me], val);
}
__device__ __forceinline__ void pod_wait(u32* ph, int pod, u32 target) {
  const int t = threadIdx.x;
  if (t < 32) {
    while (ALOADI(&ph[pod * 32 + t]) < target) { __builtin_amdgcn_s_sleep(1); }
  }
  __syncthreads();
}

__global__ __launch_bounds__(NTHR) void mono_kernel(Args a) {
  const int blk = blockIdx.x;
  const int t = threadIdx.x;
  __shared__ alignas(16) unsigned char SMRAW[42368];
  __shared__ int visS[NN];
  __shared__ float vSp[HH];
  __shared__ double logpS;
  const int grp = blk >> 5;
  const int me  = blk & 31;
  const int jb = 4 * (blk & 7) + ((blk >> 3) & 3);   // XCD-aware role swizzle
  u32* p1f = a.flags;
  u32* qf  = a.flags + 256;
  u32* p2f = a.flags + 512;

  // ============ phase 0: init + weights + kenc ============
  {
    const int tid = blk * NTHR + t;
    const int tot = NBLK * NTHR;
    if (tid < BB * HH) { a.h0[tid] = 0.0; a.c[tid] = 0.0; }
    if (tid < BB) a.idx[tid] = -1;
    if (tid < 256) {
      u32 o0, o1;
      threefry2x32(0u, 42u, 0u, (u32)tid, o0, o1);
      a.keys[2 * tid] = o0; a.keys[2 * tid + 1] = o1;
    }
    if (tid < G4) a.bsum[tid] = (double)a.b_ih[tid] + (double)a.b_hh[tid];
    for (int i = tid; i < HH * HH; i += tot) {
      int h2 = i >> 9, h = i & 511;
      a.WqT[i] = a.W_q[h * HH + h2];
    }
    for (int i = tid; i < KK * G4; i += tot) {
      int k = i >> 11, col = i & 2047;
      int x16 = col >> 6, g = (col >> 4) & 3, w = col & 15;
      int j = g * HH + x16 * 16 + w;
      a.Wc[i] = (k < EE) ? a.W_ih[j * EE + k] : a.W_hh[j * HH + (k - EE)];
    }
    if (t < NN) visS[t] = 0;
    if (t < HH) vSp[t] = a.v[t];
    if (t == 0) logpS = 0.0;
  }
  // kenc: kT[b][h][n] = sum_e enc[b][n][e] * W_k[h][e], fp64 acc (e ascending)
  {
    float (*encS)[65] = (float(*)[65])SMRAW;
    float (*wkS)[65]  = (float(*)[65])(SMRAW + 64 * 65 * 4);
    const int tn = t & 63, th = t >> 6;  // th = wave id, 0..15
    for (int tile = blk; tile < 8 * 4 * BB; tile += NBLK) {
      const int bx = tile & 7, by = (tile >> 3) & 3, b = tile >> 5;
      const int h0i = bx * 64, n0 = by * 64;
      double acc[4];
#pragma unroll
      for (int i = 0; i < 4; i++) acc[i] = 0.0;
      for (int ec = 0; ec < EE; ec += 64) {
        __syncthreads();
#pragma unroll
        for (int i = 0; i < 4; i++) {
          int idx = i * NTHR + t; int r = idx >> 6, cc = idx & 63;
          encS[r][cc] = a.enc[((size_t)b * NN + n0 + r) * EE + ec + cc];
          wkS[r][cc]  = a.W_k[(size_t)(h0i + r) * EE + ec + cc];
        }
        __syncthreads();
#pragma unroll 8
        for (int e = 0; e < 64; e++) {
          double ev = (double)encS[tn][e];
#pragma unroll
          for (int i = 0; i < 4; i++) acc[i] += (double)wkS[th * 4 + i][e] * ev;
        }
      }
#pragma unroll
      for (int i = 0; i < 4; i++)
        a.kT[((size_t)b * HH + h0i + th * 4 + i) * NN + n0 + tn] = (float)acc[i];
    }
  }
  grid_barrier(a.flags + 768, a.flags + 800);

  // ============ decode loop ============
  for (int step = 0; step < TT; step++) {
    double* hPrev = (step & 1) ? a.h1 : a.h0;
    double* hCur  = (step & 1) ? a.h0 : a.h1;
    const int b0 = grp * 32;

    if (step > 0) pod_wait(p2f, grp, (u32)step);

    // ===== Phase A: gates GEMM fused with LSTM; 2-deep prefetch rotation =====
    {
      double (*aS)[33] = (double(*)[33])SMRAW;             // 32x33x8 = 8448
      double (*bS)[66] = (double(*)[66])(SMRAW + 8448);    // 32x66x8 = 16896
      int* idxP = (int*)(SMRAW + 25344);
      const int sr = t >> 5, scp = t & 31;
      const int bk = t >> 6, bc = t & 63;
      if (t < 32) idxP[t] = ALOADI(&a.idx[b0 + t]);
      __syncthreads();

      double aRq[2]; float bR0q[2], bR1q[2];
      auto issueA = [&](int kc, int slot) {
        if (kc < EE) {
          int iv = idxP[sr];
          aRq[slot] = (iv >= 0) ? (double)a.enc[((size_t)(b0 + sr) * NN + iv) * EE + kc + scp] : 0.0;
        } else {
          aRq[slot] = ALOADD(&hPrev[(size_t)(b0 + sr) * HH + (kc - EE) + scp]);
        }
        bR0q[slot] = a.Wc[(size_t)(kc + bk)      * G4 + jb * 64 + bc];
        bR1q[slot] = a.Wc[(size_t)(kc + bk + 16) * G4 + jb * 64 + bc];
      };
      issueA(0, 0);
      issueA(32, 1);

      const int jc = t & 63, rg2 = t >> 6;
      double acc0, acc1, acc2, acc3;
      {
        double bv = a.bsum[(jc >> 4) * HH + jb * 16 + (jc & 15)];
        acc0 = bv; acc1 = bv; acc2 = bv; acc3 = bv;
      }
      for (int kc = 0; kc < KK; kc += 32) {
        const int slot = (kc >> 5) & 1;
        aS[sr][scp] = aRq[slot];
        bS[bk][bc]      = (double)bR0q[slot];
        bS[bk + 16][bc] = (double)bR1q[slot];
        if (kc + 64 < KK) issueA(kc + 64, slot);
        __syncthreads();
        if (t < 512) {
#pragma unroll 8
          for (int kk = 0; kk < 32; kk++) {
            double bv = bS[kk][jc];
            acc0 += aS[rg2 * 4][kk]     * bv;
            acc1 += aS[rg2 * 4 + 1][kk] * bv;
            acc2 += aS[rg2 * 4 + 2][kk] * bv;
            acc3 += aS[rg2 * 4 + 3][kk] * bv;
          }
        }
        __syncthreads();
      }
      double (*gS)[66] = (double(*)[66])SMRAW;
      if (t < 512) {
        gS[rg2 * 4][jc]     = acc0;
        gS[rg2 * 4 + 1][jc] = acc1;
        gS[rg2 * 4 + 2][jc] = acc2;
        gS[rg2 * 4 + 3][jc] = acc3;
      }
      __syncthreads();
      if (t < 512) {
        const int b = t >> 4, w = t & 15;
        double ig = gS[b][w], fg = gS[b][16 + w], gv = gS[b][32 + w], og = gS[b][48 + w];
        double si = 1.0 / (1.0 + exp(-ig));
        double sf = 1.0 / (1.0 + exp(-fg));
        double so = 1.0 / (1.0 + exp(-og));
        size_t ci = (size_t)(b0 + b) * HH + jb * 16 + w;
        double cn = sf * a.c[ci] + si * tanh(gv);
        a.c[ci] = cn;
        ASTORED(&hCur[ci], so * tanh(cn));
      }
    }
    pod_signal(p1f, grp, me, (u32)(step + 1));
    pod_wait(p1f, grp, (u32)(step + 1));

    // ===== Phase B: q-slice GEMM (r9-verbatim); block (jb,pod) -> q[32b x 16j] =====
    {
      double (*hS)[33] = (double(*)[33])SMRAW;             // 32x33x8 = 8448
      float  (*wS)[17] = (float (*)[17])(SMRAW + 8448);    // 32x17x4 = 2176
      const int sr = t >> 5, scp = t & 31;
      const int wk = t >> 4, wj = t & 15;
      const int j0 = jb * 16;
      double hR = ALOADD(&hCur[(size_t)(b0 + sr) * HH + scp]);
      float  wR = (t < 512) ? a.WqT[(size_t)wk * HH + j0 + wj] : 0.0f;
      const int bq = t >> 4, j = t & 15;
      double p0 = 0.0, p1 = 0.0, p2 = 0.0, p3 = 0.0;
      for (int kc = 0; kc < HH; kc += 32) {
        hS[sr][scp] = hR;
        if (t < 512) wS[wk][wj] = wR;
        int kn = kc + 32;
        if (kn < HH) {
          hR = ALOADD(&hCur[(size_t)(b0 + sr) * HH + kn + scp]);
          if (t < 512) wR = a.WqT[(size_t)(kn + wk) * HH + j0 + wj];
        }
        __syncthreads();
        if (t < 512) {
#pragma unroll 8
          for (int kk = 0; kk < 32; kk += 4) {
            p0 += hS[bq][kk]     * (double)wS[kk][j];
            p1 += hS[bq][kk + 1] * (double)wS[kk + 1][j];
            p2 += hS[bq][kk + 2] * (double)wS[kk + 2][j];
            p3 += hS[bq][kk + 3] * (double)wS[kk + 3][j];
          }
        }
        __syncthreads();
      }
      if (t < 512)
        ASTORED(&a.q[(size_t)(b0 + bq) * HH + j0 + j], (p0 + p1) + (p2 + p3));
    }
    pod_signal(qf, grp, me, (u32)(step + 1));
    pod_wait(qf, grp, (u32)(step + 1));

    // ===== Phase C: attention + gumbel sample; block = batch blk =====
    // float4-wide kT stream with 8-deep manual prefetch; early idx publish.
    {
      double* qS  = (double*)SMRAW;            // 512*8   = 4096
      double* pS  = (double*)(SMRAW + 4096);   // 16*258*8 = 33024 (stride 258)
      double* sS  = (double*)(SMRAW + 37120);  // 256*8  = 2048
      double* red = (double*)(SMRAW + 39168);  // 256*8  = 2048
      int*   redi = (int*)(SMRAW + 41216);     // 256*4  = 1024
      int*   idxS = (int*)(SMRAW + 42240);
      const int b = blk;
      if (t < 512) qS[t] = ALOADD(&a.q[(size_t)b * HH + t]);
      __syncthreads();

      // scores: slice = t>>6 (16 slices x 32 rows), col4 = (t&63)*4
      const int col4 = (t & 63) * 4, slice = t >> 6;
      const float* kp = a.kT + ((size_t)b * HH + slice * 32) * NN + col4;
      double c0 = 0.0, c1 = 0.0, c2 = 0.0, c3 = 0.0;
      float4 kv[8];
#pragma unroll
      for (int i = 0; i < 8; i++) kv[i] = *(const float4*)(kp + (size_t)i * NN);
#pragma unroll
      for (int hb = 0; hb < 32; hb += 8) {
#pragma unroll
        for (int i = 0; i < 8; i++) {
          float4 cur = kv[i];
          if (hb + 8 < 32) kv[i] = *(const float4*)(kp + (size_t)(hb + 8 + i) * NN);
          int hh = slice * 32 + hb + i;
          double qh = qS[hh];
          double vh = (double)vSp[hh];
          c0 += vh * (double)tanhf((float)(qh + (double)cur.x));
          c1 += vh * (double)tanhf((float)(qh + (double)cur.y));
          c2 += vh * (double)tanhf((float)(qh + (double)cur.z));
          c3 += vh * (double)tanhf((float)(qh + (double)cur.w));
        }
      }
      {
        double* pw = pS + slice * 258 + col4;
        pw[0] = c0; pw[1] = c1; pw[2] = c2; pw[3] = c3;
      }
      __syncthreads();

      if (t < 256) {
        double s = 0.0;
#pragma unroll
        for (int sl = 0; sl < 16; sl++) s += pS[sl * 258 + t];
        if (visS[t]) s -= 1.0e6;
        sS[t] = s;
      }
      __syncthreads();

      // gumbel: jax_threefry_partitionable=True categorical
      if (t < 256) {
        u32 fl = (u32)(b * 256 + t);
        u32 o0, o1;
        threefry2x32(a.keys[2 * step], a.keys[2 * step + 1], 0u, fl, o0, o1);
        u32 bits = o0 ^ o1;
        u32 fb = (bits >> 9) | 0x3F800000u;
        float uf = __uint_as_float(fb) - 1.0f;
        double uu = (uf > 0.0f) ? (double)uf : (double)1.17549435e-38f;
        double gmb = -log(-log(uu));
        red[t] = gmb + sS[t];
        redi[t] = t;
      }
      __syncthreads();
      for (int s2 = 128; s2 > 0; s2 >>= 1) {
        if (t < s2) {
          double v1 = red[t], v2 = red[t + s2];
          int i1 = redi[t], i2 = redi[t + s2];
          if (v2 > v1 || (v2 == v1 && i2 < i1)) { red[t] = v2; redi[t] = i2; }
        }
        __syncthreads();
      }
      if (t == 0) *idxS = redi[0];
      __syncthreads();

      // EARLY publish: idx to LLC + p2f signal (producers can start next A)
      if (t == 0) {
        int bi = *idxS;
        visS[bi] = 1;
        ASTOREI(&a.idx[b], bi);
      }
      pod_signal(p2f, grp, me, (u32)(step + 1));

      // softmax bookkeeping (off critical path)
      if (t < 256) red[t] = sS[t];
      __syncthreads();
      for (int s2 = 128; s2 > 0; s2 >>= 1) {
        if (t < s2) red[t] = fmax(red[t], red[t + s2]);
        __syncthreads();
      }
      double m = red[0];
      __syncthreads();
      if (t < 256) red[t] = exp(sS[t] - m);
      __syncthreads();
      for (int s2 = 128; s2 > 0; s2 >>= 1) {
        if (t < s2) red[t] += red[t + s2];
        __syncthreads();
      }
      if (t == 0) {
        int bi = *idxS;
        double p = exp(sS[bi] - m) / red[0];
        logpS += p;
        a.out[(size_t)b * TT + step] = (float)bi;
      }
      __syncthreads();
    }
  }

  if (t == 0) a.out[BB * TT + blk] = (float)logpS;
}

// ---------------- host launch ---------------------------------------------
extern "C" void kernel_launch(void* const* d_in, const int* in_sizes, int n_in,
                              void* d_out, int out_size, void* d_ws, size_t ws_size,
                              hipStream_t stream) {
  char* ws = (char*)d_ws;
  Args a;
  a.enc  = (const float*)d_in[0];
  a.W_ih = (const float*)d_in[1];
  a.W_hh = (const float*)d_in[2];
  a.b_ih = (const float*)d_in[3];
  a.b_hh = (const float*)d_in[4];
  a.W_q  = (const float*)d_in[5];
  a.W_k  = (const float*)d_in[6];
  a.v    = (const float*)d_in[7];
  a.out  = (float*)d_out;

  a.kT    = (float*)(ws + 0);            // 134217728
  a.Wc    = (float*)(ws + 134217728);    // 6291456
  a.WqT   = (float*)(ws + 140509184);    // 1048576
  a.bsum  = (double*)(ws + 141557760);   // 16384
  a.keys  = (u32*)(ws + 141574144);      // 2048
  a.h0    = (double*)(ws + 141576192);   // 1048576
  a.h1    = (double*)(ws + 142624768);   // 1048576
  a.c     = (double*)(ws + 143673344);   // 1048576
  a.idx   = (int*)(ws + 144721920);      // 1024
  a.flags = (u32*)(ws + 144723968);      // 4096
  a.q     = (double*)(ws + 144728064);   // 1048576

  hipMemsetAsync((void*)a.flags, 0, 4096, stream);

  void* kargs[] = { &a };
  hipLaunchCooperativeKernel(reinterpret_cast<void*>(&mono_kernel),
                             dim3(NBLK), dim3(NTHR), kargs, 0, stream);
}

// Round 16
// 28294.046 us; speedup vs baseline: 3.1219x; 3.1219x over previous
//
#include <hip/hip_runtime.h>
#include <cstdint>
#include <math.h>

typedef unsigned int u32;

#define BB 256   // batch
#define NN 256   // nodes
#define EE 256   // enc dim
#define HH 512   // hidden
#define G4 2048  // 4H
#define KK 768   // E + H
#define TT 256   // steps
#define NBLK 256
#define NTHR 1024

#define ALOADD(p)    __hip_atomic_load((p), __ATOMIC_RELAXED, __HIP_MEMORY_SCOPE_AGENT)
#define ASTORED(p,v) __hip_atomic_store((p), (v), __ATOMIC_RELAXED, __HIP_MEMORY_SCOPE_AGENT)
#define ALOADI(p)    __hip_atomic_load((p), __ATOMIC_RELAXED, __HIP_MEMORY_SCOPE_AGENT)
#define ASTOREI(p,v) __hip_atomic_store((p), (v), __ATOMIC_RELAXED, __HIP_MEMORY_SCOPE_AGENT)

// ---------------- Threefry-2x32, exactly as jax/_src/prng.py ----------------
__device__ __forceinline__ u32 rotl(u32 x, int d) { return (x << d) | (x >> (32 - d)); }

__device__ __forceinline__ void tf4(u32& x0, u32& x1, int r0, int r1, int r2, int r3) {
  x0 += x1; x1 = rotl(x1, r0); x1 ^= x0;
  x0 += x1; x1 = rotl(x1, r1); x1 ^= x0;
  x0 += x1; x1 = rotl(x1, r2); x1 ^= x0;
  x0 += x1; x1 = rotl(x1, r3); x1 ^= x0;
}

__device__ __forceinline__ void threefry2x32(u32 k0, u32 k1, u32 x0, u32 x1, u32& o0, u32& o1) {
  u32 k2 = k0 ^ k1 ^ 0x1BD11BDAu;
  x0 += k0; x1 += k1;
  tf4(x0, x1, 13, 15, 26, 6);  x0 += k1; x1 += k2 + 1u;
  tf4(x0, x1, 17, 29, 16, 24); x0 += k2; x1 += k0 + 2u;
  tf4(x0, x1, 13, 15, 26, 6);  x0 += k0; x1 += k1 + 3u;
  tf4(x0, x1, 17, 29, 16, 24); x0 += k1; x1 += k2 + 4u;
  tf4(x0, x1, 13, 15, 26, 6);  x0 += k2; x1 += k0 + 5u;
  o0 = x0; o1 = x1;
}

struct Args {
  const float *enc, *W_ih, *W_hh, *b_ih, *b_hh, *W_q, *W_k, *v;
  float *out;
  float *kT;       // [B][H][N] f32
  float *Wc;       // [K=768][2048] f32, gate-interleaved permuted columns
  float *WqT;      // [H][H] f32 k-major
  double *bsum;    // [2048]
  u32 *keys;       // [256][2]
  double *h0, *h1; // [B][H] double-buffered hidden (LLC-coherent)
  double *c;       // [B][H] (private per A-block)
  double *q;       // [B][H] fp64 q (LLC-coherent)
  int *idx;        // [B] last sampled index (LLC-coherent)
  u32 *flags;      // [0]=p1f | [256]=qf | [512]=p2f | [768]=cnt | [800]=gen
};

// Full grid barrier with cache maintenance — used ONCE after phase 0.
__device__ __forceinline__ void grid_barrier(u32* cnt, u32* gen) {
  __syncthreads();
  if (threadIdx.x == 0) {
    u32 g = __hip_atomic_load(gen, __ATOMIC_RELAXED, __HIP_MEMORY_SCOPE_AGENT);
    __threadfence();
    if (atomicAdd(cnt, 1u) == NBLK - 1u) {
      __hip_atomic_store(cnt, 0u, __ATOMIC_RELAXED, __HIP_MEMORY_SCOPE_AGENT);
      __threadfence();
      atomicAdd(gen, 1u);
    } else {
      while (__hip_atomic_load(gen, __ATOMIC_RELAXED, __HIP_MEMORY_SCOPE_AGENT) == g) {
        __builtin_amdgcn_s_sleep(2);
      }
    }
    __threadfence();
  }
  __syncthreads();
}

// Flag-array pod handoff (r9-proven).
__device__ __forceinline__ void pod_signal(u32* ph, int pod, int me, u32 val) {
  asm volatile("s_waitcnt vmcnt(0)" ::: "memory");
  __syncthreads();
  if (threadIdx.x == 0) ASTOREI(&ph[pod * 32 + me], val);
}
__device__ __forceinline__ void pod_wait(u32* ph, int pod, u32 target) {
  const int t = threadIdx.x;
  if (t < 32) {
    while (ALOADI(&ph[pod * 32 + t]) < target) { __builtin_amdgcn_s_sleep(1); }
  }
  __syncthreads();
}

__global__ __launch_bounds__(NTHR) void mono_kernel(Args a) {
  const int blk = blockIdx.x;
  const int t = threadIdx.x;
  __shared__ alignas(16) unsigned char SMRAW[42368];
  __shared__ int visS[NN];
  __shared__ float vSp[HH];
  __shared__ double logpS;
  const int grp = blk >> 5;
  const int me  = blk & 31;
  const int jb = 4 * (blk & 7) + ((blk >> 3) & 3);   // XCD-aware role swizzle
  u32* p1f = a.flags;
  u32* qf  = a.flags + 256;
  u32* p2f = a.flags + 512;

  // ============ phase 0: init + weights + kenc ============
  {
    const int tid = blk * NTHR + t;
    const int tot = NBLK * NTHR;
    if (tid < BB * HH) { a.h0[tid] = 0.0; a.c[tid] = 0.0; }
    if (tid < BB) a.idx[tid] = -1;
    if (tid < 256) {
      u32 o0, o1;
      threefry2x32(0u, 42u, 0u, (u32)tid, o0, o1);
      a.keys[2 * tid] = o0; a.keys[2 * tid + 1] = o1;
    }
    if (tid < G4) a.bsum[tid] = (double)a.b_ih[tid] + (double)a.b_hh[tid];
    for (int i = tid; i < HH * HH; i += tot) {
      int h2 = i >> 9, h = i & 511;
      a.WqT[i] = a.W_q[h * HH + h2];
    }
    for (int i = tid; i < KK * G4; i += tot) {
      int k = i >> 11, col = i & 2047;
      int x16 = col >> 6, g = (col >> 4) & 3, w = col & 15;
      int j = g * HH + x16 * 16 + w;
      a.Wc[i] = (k < EE) ? a.W_ih[j * EE + k] : a.W_hh[j * HH + (k - EE)];
    }
    if (t < NN) visS[t] = 0;
    if (t < HH) vSp[t] = a.v[t];
    if (t == 0) logpS = 0.0;
  }
  // kenc: kT[b][h][n] = sum_e enc[b][n][e] * W_k[h][e], fp64 acc (e ascending)
  {
    float (*encS)[65] = (float(*)[65])SMRAW;
    float (*wkS)[65]  = (float(*)[65])(SMRAW + 64 * 65 * 4);
    const int tn = t & 63, th = t >> 6;  // th = wave id, 0..15
    for (int tile = blk; tile < 8 * 4 * BB; tile += NBLK) {
      const int bx = tile & 7, by = (tile >> 3) & 3, b = tile >> 5;
      const int h0i = bx * 64, n0 = by * 64;
      double acc[4];
#pragma unroll
      for (int i = 0; i < 4; i++) acc[i] = 0.0;
      for (int ec = 0; ec < EE; ec += 64) {
        __syncthreads();
#pragma unroll
        for (int i = 0; i < 4; i++) {
          int idx = i * NTHR + t; int r = idx >> 6, cc = idx & 63;
          encS[r][cc] = a.enc[((size_t)b * NN + n0 + r) * EE + ec + cc];
          wkS[r][cc]  = a.W_k[(size_t)(h0i + r) * EE + ec + cc];
        }
        __syncthreads();
#pragma unroll 8
        for (int e = 0; e < 64; e++) {
          double ev = (double)encS[tn][e];
#pragma unroll
          for (int i = 0; i < 4; i++) acc[i] += (double)wkS[th * 4 + i][e] * ev;
        }
      }
#pragma unroll
      for (int i = 0; i < 4; i++)
        a.kT[((size_t)b * HH + h0i + th * 4 + i) * NN + n0 + tn] = (float)acc[i];
    }
  }
  grid_barrier(a.flags + 768, a.flags + 800);

  // ============ decode loop ============
  for (int step = 0; step < TT; step++) {
    double* hPrev = (step & 1) ? a.h1 : a.h0;
    double* hCur  = (step & 1) ? a.h0 : a.h1;
    const int b0 = grp * 32;

    if (step > 0) pod_wait(p2f, grp, (u32)step);

    // ===== Phase A: gates GEMM fused with LSTM (r9/r13-verbatim) =====
    {
      double (*aS)[33] = (double(*)[33])SMRAW;             // 32x33x8 = 8448
      double (*bS)[66] = (double(*)[66])(SMRAW + 8448);    // 32x66x8 = 16896
      int* idxP = (int*)(SMRAW + 25344);
      const int sr = t >> 5, scp = t & 31;
      const int bk = t >> 6, bc = t & 63;
      if (t < 32) idxP[t] = ALOADI(&a.idx[b0 + t]);
      __syncthreads();

      double aR; float bR0, bR1;
      {
        int iv = idxP[sr];
        aR = (iv >= 0) ? (double)a.enc[((size_t)(b0 + sr) * NN + iv) * EE + scp] : 0.0;
        bR0 = a.Wc[(size_t)(bk)      * G4 + jb * 64 + bc];
        bR1 = a.Wc[(size_t)(bk + 16) * G4 + jb * 64 + bc];
      }
      const int jc = t & 63, rg2 = t >> 6;
      double acc0, acc1, acc2, acc3;
      {
        double bv = a.bsum[(jc >> 4) * HH + jb * 16 + (jc & 15)];
        acc0 = bv; acc1 = bv; acc2 = bv; acc3 = bv;
      }
      for (int kc = 0; kc < KK; kc += 32) {
        aS[sr][scp] = aR;
        bS[bk][bc]      = (double)bR0;
        bS[bk + 16][bc] = (double)bR1;
        int kn = kc + 32;
        if (kn < KK) {
          if (kn < EE) {
            int iv = idxP[sr];
            aR = (iv >= 0) ? (double)a.enc[((size_t)(b0 + sr) * NN + iv) * EE + kn + scp] : 0.0;
          } else {
            aR = ALOADD(&hPrev[(size_t)(b0 + sr) * HH + (kn - EE) + scp]);
          }
          bR0 = a.Wc[(size_t)(kn + bk)      * G4 + jb * 64 + bc];
          bR1 = a.Wc[(size_t)(kn + bk + 16) * G4 + jb * 64 + bc];
        }
        __syncthreads();
        if (t < 512) {
#pragma unroll 8
          for (int kk = 0; kk < 32; kk++) {
            double bv = bS[kk][jc];
            acc0 += aS[rg2 * 4][kk]     * bv;
            acc1 += aS[rg2 * 4 + 1][kk] * bv;
            acc2 += aS[rg2 * 4 + 2][kk] * bv;
            acc3 += aS[rg2 * 4 + 3][kk] * bv;
          }
        }
        __syncthreads();
      }
      double (*gS)[66] = (double(*)[66])SMRAW;
      if (t < 512) {
        gS[rg2 * 4][jc]     = acc0;
        gS[rg2 * 4 + 1][jc] = acc1;
        gS[rg2 * 4 + 2][jc] = acc2;
        gS[rg2 * 4 + 3][jc] = acc3;
      }
      __syncthreads();
      if (t < 512) {
        const int b = t >> 4, w = t & 15;
        double ig = gS[b][w], fg = gS[b][16 + w], gv = gS[b][32 + w], og = gS[b][48 + w];
        double si = 1.0 / (1.0 + exp(-ig));
        double sf = 1.0 / (1.0 + exp(-fg));
        double so = 1.0 / (1.0 + exp(-og));
        size_t ci = (size_t)(b0 + b) * HH + jb * 16 + w;
        double cn = sf * a.c[ci] + si * tanh(gv);
        a.c[ci] = cn;
        ASTORED(&hCur[ci], so * tanh(cn));
      }
    }
    pod_signal(p1f, grp, me, (u32)(step + 1));
    pod_wait(p1f, grp, (u32)(step + 1));

    // ===== Phase B: q-slice GEMM (r9-verbatim); block (jb,pod) -> q[32b x 16j] =====
    {
      double (*hS)[33] = (double(*)[33])SMRAW;             // 32x33x8 = 8448
      float  (*wS)[17] = (float (*)[17])(SMRAW + 8448);    // 32x17x4 = 2176
      const int sr = t >> 5, scp = t & 31;
      const int wk = t >> 4, wj = t & 15;
      const int j0 = jb * 16;
      double hR = ALOADD(&hCur[(size_t)(b0 + sr) * HH + scp]);
      float  wR = (t < 512) ? a.WqT[(size_t)wk * HH + j0 + wj] : 0.0f;
      const int bq = t >> 4, j = t & 15;
      double p0 = 0.0, p1 = 0.0, p2 = 0.0, p3 = 0.0;
      for (int kc = 0; kc < HH; kc += 32) {
        hS[sr][scp] = hR;
        if (t < 512) wS[wk][wj] = wR;
        int kn = kc + 32;
        if (kn < HH) {
          hR = ALOADD(&hCur[(size_t)(b0 + sr) * HH + kn + scp]);
          if (t < 512) wR = a.WqT[(size_t)(kn + wk) * HH + j0 + wj];
        }
        __syncthreads();
        if (t < 512) {
#pragma unroll 8
          for (int kk = 0; kk < 32; kk += 4) {
            p0 += hS[bq][kk]     * (double)wS[kk][j];
            p1 += hS[bq][kk + 1] * (double)wS[kk + 1][j];
            p2 += hS[bq][kk + 2] * (double)wS[kk + 2][j];
            p3 += hS[bq][kk + 3] * (double)wS[kk + 3][j];
          }
        }
        __syncthreads();
      }
      if (t < 512)
        ASTORED(&a.q[(size_t)(b0 + bq) * HH + j0 + j], (p0 + p1) + (p2 + p3));
    }
    pod_signal(qf, grp, me, (u32)(step + 1));
    pod_wait(qf, grp, (u32)(step + 1));

    // ===== Phase C: attention + gumbel sample; block = batch blk =====
    // r13-verbatim float4 kT stream; EARLY idx publish + p2f signal after
    // argmax; softmax/logp bookkeeping off the critical path.
    {
      double* qS  = (double*)SMRAW;            // 512*8   = 4096
      double* pS  = (double*)(SMRAW + 4096);   // 16*258*8 = 33024 (stride 258)
      double* sS  = (double*)(SMRAW + 37120);  // 256*8  = 2048
      double* red = (double*)(SMRAW + 39168);  // 256*8  = 2048
      int*   redi = (int*)(SMRAW + 41216);     // 256*4  = 1024
      int*   idxS = (int*)(SMRAW + 42240);
      const int b = blk;
      if (t < 512) qS[t] = ALOADD(&a.q[(size_t)b * HH + t]);
      __syncthreads();

      // scores: slice = t>>6 (16 slices x 32 rows), col4 = (t&63)*4
      const int col4 = (t & 63) * 4, slice = t >> 6;
      const float* kp = a.kT + ((size_t)b * HH + slice * 32) * NN + col4;
      double c0 = 0.0, c1 = 0.0, c2 = 0.0, c3 = 0.0;
#pragma unroll 4
      for (int h = 0; h < 32; h++) {
        float4 kv = *(const float4*)(kp + (size_t)h * NN);
        int hh = slice * 32 + h;
        double qh = qS[hh];
        double vh = (double)vSp[hh];
        c0 += vh * (double)tanhf((float)(qh + (double)kv.x));
        c1 += vh * (double)tanhf((float)(qh + (double)kv.y));
        c2 += vh * (double)tanhf((float)(qh + (double)kv.z));
        c3 += vh * (double)tanhf((float)(qh + (double)kv.w));
      }
      {
        double* pw = pS + slice * 258 + col4;
        pw[0] = c0; pw[1] = c1; pw[2] = c2; pw[3] = c3;
      }
      __syncthreads();

      if (t < 256) {
        double s = 0.0;
#pragma unroll
        for (int sl = 0; sl < 16; sl++) s += pS[sl * 258 + t];
        if (visS[t]) s -= 1.0e6;
        sS[t] = s;
      }
      __syncthreads();

      // gumbel: jax_threefry_partitionable=True categorical
      if (t < 256) {
        u32 fl = (u32)(b * 256 + t);
        u32 o0, o1;
        threefry2x32(a.keys[2 * step], a.keys[2 * step + 1], 0u, fl, o0, o1);
        u32 bits = o0 ^ o1;
        u32 fb = (bits >> 9) | 0x3F800000u;
        float uf = __uint_as_float(fb) - 1.0f;
        double uu = (uf > 0.0f) ? (double)uf : (double)1.17549435e-38f;
        double gmb = -log(-log(uu));
        red[t] = gmb + sS[t];
        redi[t] = t;
      }
      __syncthreads();
      for (int s2 = 128; s2 > 0; s2 >>= 1) {
        if (t < s2) {
          double v1 = red[t], v2 = red[t + s2];
          int i1 = redi[t], i2 = redi[t + s2];
          if (v2 > v1 || (v2 == v1 && i2 < i1)) { red[t] = v2; redi[t] = i2; }
        }
        __syncthreads();
      }
      if (t == 0) *idxS = redi[0];
      __syncthreads();

      // EARLY publish: idx to LLC + p2f signal (producers start next step's A)
      if (t == 0) {
        int bi = *idxS;
        visS[bi] = 1;
        ASTOREI(&a.idx[b], bi);
      }
      pod_signal(p2f, grp, me, (u32)(step + 1));

      // softmax bookkeeping (off critical path; sS already latched in LDS)
      if (t < 256) red[t] = sS[t];
      __syncthreads();
      for (int s2 = 128; s2 > 0; s2 >>= 1) {
        if (t < s2) red[t] = fmax(red[t], red[t + s2]);
        __syncthreads();
      }
      double m = red[0];
      __syncthreads();
      if (t < 256) red[t] = exp(sS[t] - m);
      __syncthreads();
      for (int s2 = 128; s2 > 0; s2 >>= 1) {
        if (t < s2) red[t] += red[t + s2];
        __syncthreads();
      }
      if (t == 0) {
        int bi = *idxS;
        double p = exp(sS[bi] - m) / red[0];
        logpS += p;
        a.out[(size_t)b * TT + step] = (float)bi;
      }
      __syncthreads();
    }
  }

  if (t == 0) a.out[BB * TT + blk] = (float)logpS;
}

// ---------------- host launch ---------------------------------------------
extern "C" void kernel_launch(void* const* d_in, const int* in_sizes, int n_in,
                              void* d_out, int out_size, void* d_ws, size_t ws_size,
                              hipStream_t stream) {
  char* ws = (char*)d_ws;
  Args a;
  a.enc  = (const float*)d_in[0];
  a.W_ih = (const float*)d_in[1];
  a.W_hh = (const float*)d_in[2];
  a.b_ih = (const float*)d_in[3];
  a.b_hh = (const float*)d_in[4];
  a.W_q  = (const float*)d_in[5];
  a.W_k  = (const float*)d_in[6];
  a.v    = (const float*)d_in[7];
  a.out  = (float*)d_out;

  a.kT    = (float*)(ws + 0);            // 134217728
  a.Wc    = (float*)(ws + 134217728);    // 6291456
  a.WqT   = (float*)(ws + 140509184);    // 1048576
  a.bsum  = (double*)(ws + 141557760);   // 16384
  a.keys  = (u32*)(ws + 141574144);      // 2048
  a.h0    = (double*)(ws + 141576192);   // 1048576
  a.h1    = (double*)(ws + 142624768);   // 1048576
  a.c     = (double*)(ws + 143673344);   // 1048576
  a.idx   = (int*)(ws + 144721920);      // 1024
  a.flags = (u32*)(ws + 144723968);      // 4096
  a.q     = (double*)(ws + 144728064);   // 1048576

  hipMemsetAsync((void*)a.flags, 0, 4096, stream);

  void* kargs[] = { &a };
  hipLaunchCooperativeKernel(reinterpret_cast<void*>(&mono_kernel),
                             dim3(NBLK), dim3(NTHR), kargs, 0, stream);
}